// Round 6
// baseline (633.736 us; speedup 1.0000x reference)
//
#include <hip/hip_runtime.h>

#define BATCH 16
#define NN 512   // n  (j index, "nxt" side; rows of X)
#define MM 512   // m  (i index, "cur" side; cols of X)
#define DD 128
#define QP_ITERS 20
#define NSLOTS (BATCH * 16)  // 256 chunk slots (16 per batch)
#define SLOT 1024            // floats per chunk slot (512 x-partials + 512 qx)

// ---------------------------------------------------------------------------
// row_norms: rc[b*512+p] = ||nc[b,p]||^2 + ||ec[b,p]||^2
//            rn[b*512+p] = ||nn[b,p]||^2 + ||en[b,p]||^2
// ---------------------------------------------------------------------------
__global__ __launch_bounds__(64) void row_norms_kernel(
    const float* __restrict__ nc, const float* __restrict__ ec,
    const float* __restrict__ nn, const float* __restrict__ en,
    float* __restrict__ rc, float* __restrict__ rn)
{
    int row = blockIdx.x;            // b*512 + p
    int t   = threadIdx.x;           // 0..63
    size_t base = (size_t)row * DD;

    float2 a = ((const float2*)(nc + base))[t];
    float2 b = ((const float2*)(ec + base))[t];
    float vc = a.x*a.x + a.y*a.y + b.x*b.x + b.y*b.y;

    float2 c = ((const float2*)(nn + base))[t];
    float2 d = ((const float2*)(en + base))[t];
    float vn = c.x*c.x + c.y*c.y + d.x*d.x + d.y*d.y;

    #pragma unroll
    for (int off = 32; off; off >>= 1) {
        vc += __shfl_down(vc, off);
        vn += __shfl_down(vn, off);
    }
    if (t == 0) { rc[row] = vc; rn[row] = vn; }
}

// ---------------------------------------------------------------------------
// gemm_q: qm[b,j,i] = 0.5*(rc[b,i]+rn[b,j]) - (nc_i . nn_j + ec_i . en_j)
// ---------------------------------------------------------------------------
__global__ __launch_bounds__(256) void gemm_q_kernel(
    const float* __restrict__ nc, const float* __restrict__ ec,
    const float* __restrict__ nn, const float* __restrict__ en,
    const float* __restrict__ rc, const float* __restrict__ rn,
    float* __restrict__ qm, float* __restrict__ sumq, float* __restrict__ sumq2)
{
    int b  = blockIdx.z;
    int it = blockIdx.x;   // i tile (cur), 64 wide
    int jt = blockIdx.y;   // j tile (nxt), 64 wide
    int tid = threadIdx.x;
    int tx = tid & 15, ty = tid >> 4;

    __shared__ float As[64][17];
    __shared__ float Bs[64][17];

    float acc[4][4] = {};

    const float* a0 = nn + ((size_t)b*NN + jt*64) * DD;
    const float* a1 = en + ((size_t)b*NN + jt*64) * DD;
    const float* b0 = nc + ((size_t)b*MM + it*64) * DD;
    const float* b1 = ec + ((size_t)b*MM + it*64) * DD;

    int lrow = tid >> 4;   // 0..15
    int lk   = tid & 15;   // 0..15

    for (int mat = 0; mat < 2; ++mat) {
        const float* ap = mat ? a1 : a0;
        const float* bp = mat ? b1 : b0;
        for (int kc = 0; kc < DD; kc += 16) {
            __syncthreads();
            #pragma unroll
            for (int r = 0; r < 4; ++r) {
                int row = lrow + r*16;
                As[row][lk] = ap[(size_t)row*DD + kc + lk];
                Bs[row][lk] = bp[(size_t)row*DD + kc + lk];
            }
            __syncthreads();
            #pragma unroll
            for (int k = 0; k < 16; ++k) {
                float ar[4], br[4];
                #pragma unroll
                for (int r = 0; r < 4; ++r) ar[r] = As[ty*4 + r][k];
                #pragma unroll
                for (int c = 0; c < 4; ++c) br[c] = Bs[tx*4 + c][k];
                #pragma unroll
                for (int r = 0; r < 4; ++r)
                    #pragma unroll
                    for (int c = 0; c < 4; ++c)
                        acc[r][c] += ar[r] * br[c];
            }
        }
    }

    float qs = 0.f, q2s = 0.f;
    #pragma unroll
    for (int r = 0; r < 4; ++r) {
        int j = jt*64 + ty*4 + r;
        float rnj = rn[b*NN + j];
        float4 o;
        float v;
        int i0 = it*64 + tx*4;
        v = 0.5f*(rc[b*MM + i0 + 0] + rnj) - acc[r][0]; o.x = v; qs += v; q2s += v*v;
        v = 0.5f*(rc[b*MM + i0 + 1] + rnj) - acc[r][1]; o.y = v; qs += v; q2s += v*v;
        v = 0.5f*(rc[b*MM + i0 + 2] + rnj) - acc[r][2]; o.z = v; qs += v; q2s += v*v;
        v = 0.5f*(rc[b*MM + i0 + 3] + rnj) - acc[r][3]; o.w = v; qs += v; q2s += v*v;
        *(float4*)(qm + ((size_t)b*NN + j)*MM + i0) = o;
    }

    #pragma unroll
    for (int off = 32; off; off >>= 1) {
        qs  += __shfl_down(qs,  off);
        q2s += __shfl_down(q2s, off);
    }
    __shared__ float red[8];
    int wid = tid >> 6, lane = tid & 63;
    if (lane == 0) { red[wid] = qs; red[4 + wid] = q2s; }
    __syncthreads();
    if (tid == 0) {
        atomicAdd(&sumq[b],  red[0] + red[1] + red[2] + red[3]);
        atomicAdd(&sumq2[b], red[4] + red[5] + red[6] + red[7]);
    }
}

// ---------------------------------------------------------------------------
__global__ __launch_bounds__(256) void zero_ws_kernel(float* __restrict__ z, int n)
{
    int idx = blockIdx.x * blockDim.x + threadIdx.x;
    if (idx < n) z[idx] = 0.f;
}

__global__ void init_scalars_kernel(const float* __restrict__ sumq,
                                    const float* __restrict__ sumq2,
                                    float* __restrict__ lrbuf, float* __restrict__ s1buf)
{
    int b = threadIdx.x;
    if (b < BATCH) {
        lrbuf[b] = 0.5f / (sumq2[b] + 1e-8f);
        s1buf[b] = sumq[b] * (1.0f / (float)MM);   // s1 = sum(qm)/m  (X0 = 1/m)
    }
}

// ---------------------------------------------------------------------------
// poll batch b's 16 flags until all >= tt (wave 0 polls, block barrier after)
// ---------------------------------------------------------------------------
__device__ __forceinline__ void poll_flags(unsigned* bflags, unsigned tt,
                                           int w, int lane)
{
    if (w == 0) {
        for (;;) {
            unsigned v = (lane < 16)
                ? __hip_atomic_load(bflags + lane, __ATOMIC_ACQUIRE,
                                    __HIP_MEMORY_SCOPE_AGENT)
                : tt;
            if (__all(v >= tt)) break;
        }
    }
    __syncthreads();
}

// ---------------------------------------------------------------------------
// gather prev iteration's partials for batch b into stage (f | colq),
// return s = sum_i f_i * colq_i. Polls flags first.
// ---------------------------------------------------------------------------
__device__ __forceinline__ float gather_fs(
    int t, int b, const float* part, float* stage, float* wred,
    unsigned* flags, int tid, int w, int lane)
{
    poll_flags(flags + b * 32, (unsigned)(t - 1), w, lane);

    const float* p = part + (size_t)((t - 1) & 1) * (NSLOTS * SLOT)
                   + (size_t)b * (16 * SLOT) + tid;
    float acc = 0.f;
    #pragma unroll
    for (int g2 = 0; g2 < 16; ++g2)
        acc += __hip_atomic_load((float*)(p + g2 * SLOT), __ATOMIC_RELAXED,
                                 __HIP_MEMORY_SCOPE_AGENT);
    if (tid < 512) stage[tid] = fminf(1.0f, 2.0f / (acc + 1e-8f));   // f
    else           stage[tid] = acc;                                 // colq
    __syncthreads();
    float v = (tid < 512) ? stage[tid] * stage[512 + tid] : 0.f;
    #pragma unroll
    for (int m = 32; m; m >>= 1) v += __shfl_xor(v, m);
    if (lane == 0) wred[w] = v;
    __syncthreads();
    float s = 0.f;
    #pragma unroll
    for (int i = 0; i < 16; ++i) s += wred[i];
    return s;
}

// ---------------------------------------------------------------------------
// one PGD step for one chunk: grad + clip + row-normalize, column partial
// pass through LDS, store partials to private slot, release flag.
// ---------------------------------------------------------------------------
template <bool FIRST>
__device__ __forceinline__ void qp_step(
    int t, int slot, float lr, float s, const float* stage,
    float (&q)[16], float (&x)[16],
    float* lds_part, float* part, unsigned* myflag,
    int tid, int w, int lane, int cseg)
{
    float c = 2.0f * lr * s;
    float rp = 0.f;
    #pragma unroll
    for (int k = 0; k < 16; ++k) {
        float fk = FIRST ? 1.0f : stage[cseg + 32*k];
        float v = x[k] * fk - c * q[k];
        v = fminf(fmaxf(v, 0.f), 1.f);
        x[k] = v;
        rp += v;
    }
    #pragma unroll
    for (int m = 16; m; m >>= 1) rp += __shfl_xor(rp, m);
    float inv = 1.0f / (rp + 1e-8f);
    #pragma unroll
    for (int k = 0; k < 16; ++k) x[k] *= inv;

    __syncthreads();   // prior phase's lds_part reads complete
    #pragma unroll
    for (int k = 0; k < 16; ++k) {
        float qx = q[k] * x[k];
        float px = x[k] + __shfl_xor(x[k], 32);   // row-pair sum
        float pq = qx   + __shfl_xor(qx,   32);
        int col = cseg + 32*k;
        if (lane < 32) lds_part[w * 512 + col]        = px;   // x partials
        else           lds_part[8192 + w * 512 + col] = pq;   // qx partials
    }
    __syncthreads();
    {
        int arr = tid >> 9;          // 0 => colsum(x), 1 => colsum(qx)
        int col = tid & 511;
        const float* bp = lds_part + arr * 8192 + col;
        float acc = 0.f;
        #pragma unroll
        for (int w2 = 0; w2 < 16; ++w2) acc += bp[w2 * 512];
        float* dst = part + (size_t)(t & 1) * (NSLOTS * SLOT)
                   + (size_t)slot * SLOT + tid;
        __hip_atomic_store(dst, acc, __ATOMIC_RELAXED,
                           __HIP_MEMORY_SCOPE_AGENT);
    }
    __syncthreads();   // compiler emits vmcnt(0) drain before s_barrier
    if (tid == 0)
        __hip_atomic_store(myflag, (unsigned)t, __ATOMIC_RELEASE,
                           __HIP_MEMORY_SCOPE_AGENT);
}

// ---------------------------------------------------------------------------
// final: gather last colsum, apply lazy column scale, write out
// ---------------------------------------------------------------------------
__device__ __forceinline__ void final_out(
    int b, int g, const float* part, float* stage, unsigned* flags,
    float (&x)[16], float* out, int tid, int w, int lane, int cseg)
{
    poll_flags(flags + b * 32, (unsigned)QP_ITERS, w, lane);
    if (tid < 512) {
        const float* p = part + (size_t)(QP_ITERS & 1) * (NSLOTS * SLOT)
                       + (size_t)b * (16 * SLOT) + tid;
        float acc = 0.f;
        #pragma unroll
        for (int g2 = 0; g2 < 16; ++g2)
            acc += __hip_atomic_load((float*)(p + g2 * SLOT), __ATOMIC_RELAXED,
                                     __HIP_MEMORY_SCOPE_AGENT);
        stage[tid] = fminf(1.0f, 2.0f / (acc + 1e-8f));
    }
    __syncthreads();
    int j = g * 32 + (tid >> 5);
    size_t rowbase = ((size_t)b * NN + j) * MM;
    #pragma unroll
    for (int k = 0; k < 16; ++k)
        out[rowbase + cseg + 32*k] = x[k] * stage[cseg + 32*k];
}

// ---------------------------------------------------------------------------
// qp_iter_kernel v5: dual-batch interleaved persistent PGD solve.
// 128 blocks x 1024 threads. Block (b0,g) also owns (b0+8,g); while batch
// b0's flags/partials propagate through the LLC, the block computes batch
// b1's phase — sync latency hides behind the other batch's compute.
// qm and X register-resident: 2 x 16 q + 2 x 16 x per thread.
// ---------------------------------------------------------------------------
__global__ __launch_bounds__(1024, 4) void qp_iter_kernel(
    const float* __restrict__ qm, const float* __restrict__ lrbuf,
    const float* __restrict__ s1buf, float* __restrict__ part,
    unsigned* __restrict__ flags, float* __restrict__ out)
{
    __shared__ float lds[16384 + 1024 + 1024 + 16];
    float* lds_part = lds;             // 16384: column partial matrices
    float* stage0   = lds + 16384;     // 1024: batch b0 f | colq
    float* stage1   = lds + 17408;     // 1024: batch b1 f | colq
    float* wred     = lds + 18432;     // 16

    int tid  = threadIdx.x;
    int blk  = blockIdx.x;             // 0..127
    int b0   = blk >> 4;               // 0..7
    int b1   = b0 + 8;
    int g    = blk & 15;
    int w    = tid >> 6;
    int lane = tid & 63;
    int r_loc = tid >> 5;              // 0..31 local row
    int cseg  = tid & 31;              // owns cols cseg + 32k
    int slot0 = b0 * 16 + g;
    int slot1 = b1 * 16 + g;

    const float lr0 = lrbuf[b0];
    const float lr1 = lrbuf[b1];
    size_t rowbase0 = ((size_t)b0 * NN + g * 32 + r_loc) * MM;
    size_t rowbase1 = ((size_t)b1 * NN + g * 32 + r_loc) * MM;

    float q0[16], q1[16], x0[16], x1[16];
    #pragma unroll
    for (int k = 0; k < 16; ++k) {
        q0[k] = qm[rowbase0 + cseg + 32*k];
        q1[k] = qm[rowbase1 + cseg + 32*k];
    }
    const float inv_m = 1.0f / (float)MM;
    #pragma unroll
    for (int k = 0; k < 16; ++k) { x0[k] = inv_m; x1[k] = inv_m; }

    unsigned* myflag0 = flags + b0 * 32 + g;
    unsigned* myflag1 = flags + b1 * 32 + g;

    // ---- iteration 1 (f = 1, s from s1buf) ----
    qp_step<true>(1, slot0, lr0, s1buf[b0], stage0, q0, x0,
                  lds_part, part, myflag0, tid, w, lane, cseg);
    qp_step<true>(1, slot1, lr1, s1buf[b1], stage1, q1, x1,
                  lds_part, part, myflag1, tid, w, lane, cseg);

    for (int t = 2; t <= QP_ITERS; ++t) {
        float s0 = gather_fs(t, b0, part, stage0, wred, flags, tid, w, lane);
        qp_step<false>(t, slot0, lr0, s0, stage0, q0, x0,
                       lds_part, part, myflag0, tid, w, lane, cseg);
        float s1 = gather_fs(t, b1, part, stage1, wred, flags, tid, w, lane);
        qp_step<false>(t, slot1, lr1, s1, stage1, q1, x1,
                       lds_part, part, myflag1, tid, w, lane, cseg);
    }

    final_out(b0, g, part, stage0, flags, x0, out, tid, w, lane, cseg);
    final_out(b1, g, part, stage1, flags, x1, out, tid, w, lane, cseg);
}

// ---------------------------------------------------------------------------
extern "C" void kernel_launch(void* const* d_in, const int* in_sizes, int n_in,
                              void* d_out, int out_size, void* d_ws, size_t ws_size,
                              hipStream_t stream)
{
    const float* nc = (const float*)d_in[0];  // n_emb_cur (16,512,128)
    const float* ec = (const float*)d_in[1];  // e_emb_cur
    const float* nn = (const float*)d_in[2];  // n_emb_nxt
    const float* en = (const float*)d_in[3];  // e_emb_nxt
    float* out = (float*)d_out;               // (16, 512*512) fp32

    float* ws = (float*)d_ws;
    const size_t QM_FLOATS = (size_t)BATCH * NN * MM;       // 4,194,304

    float* qm   = ws;
    float* part = ws + QM_FLOATS;                           // 2*NSLOTS*SLOT floats
    // contiguous zero region: sumq, sumq2, flags
    float* zreg  = part + (size_t)2 * NSLOTS * SLOT;
    float* sumq  = zreg;                                    // 16
    float* sumq2 = zreg + 16;                               // 16
    unsigned* flags = (unsigned*)(zreg + 32);               // 16*32 words
    const int ZN = 32 + BATCH * 32;                         // 544
    float* rc    = zreg + 576;                              // 8192
    float* rn    = rc + BATCH * MM;                         // 8192
    float* lrbuf = rn + BATCH * NN;                         // 16
    float* s1buf = lrbuf + 16;                              // 16

    zero_ws_kernel<<<3, 256, 0, stream>>>(zreg, ZN);
    row_norms_kernel<<<BATCH * 512, 64, 0, stream>>>(nc, ec, nn, en, rc, rn);
    gemm_q_kernel<<<dim3(8, 8, BATCH), 256, 0, stream>>>(nc, ec, nn, en, rc, rn,
                                                         qm, sumq, sumq2);
    init_scalars_kernel<<<1, 64, 0, stream>>>(sumq, sumq2, lrbuf, s1buf);

    void* args[] = { (void*)&qm, (void*)&lrbuf, (void*)&s1buf,
                     (void*)&part, (void*)&flags, (void*)&out };
    hipLaunchCooperativeKernel((const void*)qp_iter_kernel,
                               dim3(BATCH * 8), dim3(1024),
                               args, 0, stream);
}

// Round 7
// 381.536 us; speedup vs baseline: 1.6610x; 1.6610x over previous
//
#include <hip/hip_runtime.h>

#define BATCH 16
#define NN 512   // n  (j index, "nxt" side; rows of X)
#define MM 512   // m  (i index, "cur" side; cols of X)
#define DD 128
#define QP_ITERS 20
#define NBLK (BATCH * 16)   // 256 qp blocks, 1 per CU
#define SLOT 1024           // floats per block slot (512 x-partials + 512 qx)

// ---------------------------------------------------------------------------
// row_norms: rc[b*512+p] = ||nc[b,p]||^2 + ||ec[b,p]||^2
//            rn[b*512+p] = ||nn[b,p]||^2 + ||en[b,p]||^2
// ---------------------------------------------------------------------------
__global__ __launch_bounds__(64) void row_norms_kernel(
    const float* __restrict__ nc, const float* __restrict__ ec,
    const float* __restrict__ nn, const float* __restrict__ en,
    float* __restrict__ rc, float* __restrict__ rn)
{
    int row = blockIdx.x;            // b*512 + p
    int t   = threadIdx.x;           // 0..63
    size_t base = (size_t)row * DD;

    float2 a = ((const float2*)(nc + base))[t];
    float2 b = ((const float2*)(ec + base))[t];
    float vc = a.x*a.x + a.y*a.y + b.x*b.x + b.y*b.y;

    float2 c = ((const float2*)(nn + base))[t];
    float2 d = ((const float2*)(en + base))[t];
    float vn = c.x*c.x + c.y*c.y + d.x*d.x + d.y*d.y;

    #pragma unroll
    for (int off = 32; off; off >>= 1) {
        vc += __shfl_down(vc, off);
        vn += __shfl_down(vn, off);
    }
    if (t == 0) { rc[row] = vc; rn[row] = vn; }
}

// ---------------------------------------------------------------------------
// gemm_q v2: qm[b,j,i] = 0.5*(rc[b,i]+rn[b,j]) - (nc_i.nn_j + ec_i.en_j)
// 128x128 tile per 256-thread block, 8x8 micro-tile, K=256 (nc|ec concat),
// k-major LDS tiles, register-prefetch double buffering.
// Also accumulates sum(qm), sum(qm^2) per batch (2 atomics/block).
// ---------------------------------------------------------------------------
__global__ __launch_bounds__(256, 1) void gemm_q_kernel(
    const float* __restrict__ nc, const float* __restrict__ ec,
    const float* __restrict__ nn, const float* __restrict__ en,
    const float* __restrict__ rc, const float* __restrict__ rn,
    float* __restrict__ qm, float* __restrict__ sumq, float* __restrict__ sumq2)
{
    int b  = blockIdx.z;
    int it = blockIdx.x;   // i tile (cur), 128 wide, 0..3
    int jt = blockIdx.y;   // j tile (nxt), 128 wide, 0..3
    int tid = threadIdx.x;
    int tx = tid & 15, ty = tid >> 4;    // 16x16 threads, 8x8 micro each

    __shared__ float As[8][128];   // k-major: A[k][j-row]
    __shared__ float Bs[8][128];   // k-major: B[k][i-row]

    float acc[8][8] = {};

    int srow = tid & 127;          // staging row 0..127
    int sk4  = (tid >> 7) * 4;     // staging k offset: 0 or 4

    const float* aBase[2] = { nn + ((size_t)b*NN + jt*128) * DD,
                              en + ((size_t)b*NN + jt*128) * DD };
    const float* bBase[2] = { nc + ((size_t)b*MM + it*128) * DD,
                              ec + ((size_t)b*MM + it*128) * DD };

    // prefetch stage 0
    float4 pa = *(const float4*)(aBase[0] + (size_t)srow * DD + sk4);
    float4 pb = *(const float4*)(bBase[0] + (size_t)srow * DD + sk4);

    for (int stage = 0; stage < 32; ++stage) {
        __syncthreads();   // prior stage's LDS reads complete
        As[sk4+0][srow] = pa.x; As[sk4+1][srow] = pa.y;
        As[sk4+2][srow] = pa.z; As[sk4+3][srow] = pa.w;
        Bs[sk4+0][srow] = pb.x; Bs[sk4+1][srow] = pb.y;
        Bs[sk4+2][srow] = pb.z; Bs[sk4+3][srow] = pb.w;
        __syncthreads();

        if (stage + 1 < 32) {      // prefetch next stage while computing
            int s   = stage + 1;
            int mat = s >> 4;
            int kc  = (s & 15) * 8;
            pa = *(const float4*)(aBase[mat] + (size_t)srow * DD + kc + sk4);
            pb = *(const float4*)(bBase[mat] + (size_t)srow * DD + kc + sk4);
        }

        #pragma unroll
        for (int k = 0; k < 8; ++k) {
            float af[8], bf[8];
            *(float4*)&af[0] = *(const float4*)&As[k][ty*8];
            *(float4*)&af[4] = *(const float4*)&As[k][ty*8+4];
            *(float4*)&bf[0] = *(const float4*)&Bs[k][tx*8];
            *(float4*)&bf[4] = *(const float4*)&Bs[k][tx*8+4];
            #pragma unroll
            for (int r = 0; r < 8; ++r)
                #pragma unroll
                for (int c = 0; c < 8; ++c)
                    acc[r][c] += af[r] * bf[c];
        }
    }

    // epilogue: qm = 0.5*(rc_i + rn_j) - dot, + sum / sum-of-squares
    float rci[8];
    int i0 = it*128 + tx*8;
    #pragma unroll
    for (int c = 0; c < 8; ++c) rci[c] = rc[b*MM + i0 + c];

    float qs = 0.f, q2s = 0.f;
    #pragma unroll
    for (int r = 0; r < 8; ++r) {
        int j = jt*128 + ty*8 + r;
        float rnj = rn[b*NN + j];
        size_t rowp = ((size_t)b*NN + j)*MM + i0;
        float4 o0, o1;
        float v;
        v = 0.5f*(rci[0] + rnj) - acc[r][0]; o0.x = v; qs += v; q2s += v*v;
        v = 0.5f*(rci[1] + rnj) - acc[r][1]; o0.y = v; qs += v; q2s += v*v;
        v = 0.5f*(rci[2] + rnj) - acc[r][2]; o0.z = v; qs += v; q2s += v*v;
        v = 0.5f*(rci[3] + rnj) - acc[r][3]; o0.w = v; qs += v; q2s += v*v;
        v = 0.5f*(rci[4] + rnj) - acc[r][4]; o1.x = v; qs += v; q2s += v*v;
        v = 0.5f*(rci[5] + rnj) - acc[r][5]; o1.y = v; qs += v; q2s += v*v;
        v = 0.5f*(rci[6] + rnj) - acc[r][6]; o1.z = v; qs += v; q2s += v*v;
        v = 0.5f*(rci[7] + rnj) - acc[r][7]; o1.w = v; qs += v; q2s += v*v;
        *(float4*)(qm + rowp)     = o0;
        *(float4*)(qm + rowp + 4) = o1;
    }

    #pragma unroll
    for (int off = 32; off; off >>= 1) {
        qs  += __shfl_down(qs,  off);
        q2s += __shfl_down(q2s, off);
    }
    __shared__ float red[8];
    int wid = tid >> 6, lane = tid & 63;
    if (lane == 0) { red[wid] = qs; red[4 + wid] = q2s; }
    __syncthreads();
    if (tid == 0) {
        atomicAdd(&sumq[b],  red[0] + red[1] + red[2] + red[3]);
        atomicAdd(&sumq2[b], red[4] + red[5] + red[6] + red[7]);
    }
}

// ---------------------------------------------------------------------------
__global__ __launch_bounds__(256) void zero_ws_kernel(float* __restrict__ z, int n)
{
    int idx = blockIdx.x * blockDim.x + threadIdx.x;
    if (idx < n) z[idx] = 0.f;
}

__global__ void init_scalars_kernel(const float* __restrict__ sumq,
                                    const float* __restrict__ sumq2,
                                    float* __restrict__ lrbuf, float* __restrict__ s1buf)
{
    int b = threadIdx.x;
    if (b < BATCH) {
        lrbuf[b] = 0.5f / (sumq2[b] + 1e-8f);
        s1buf[b] = sumq[b] * (1.0f / (float)MM);   // s1 = sum(qm)/m  (X0 = 1/m)
    }
}

// ---------------------------------------------------------------------------
// qp_iter_kernel (R5-proven): persistent 20-iteration PGD solve.
// 256 blocks x 1024 threads; qm and X register-resident (16 elems/thread,
// strided columns i = cseg + 32k). Per-batch RMW-free flag sync; private
// per-block partial slots (relaxed agent stores, parity double-buffered).
// ---------------------------------------------------------------------------
__global__ __launch_bounds__(1024, 4) void qp_iter_kernel(
    const float* __restrict__ qm, const float* __restrict__ lrbuf,
    const float* __restrict__ s1buf, float* __restrict__ part,
    unsigned* __restrict__ flags, float* __restrict__ out)
{
    __shared__ float lds[16384 + 32];        // 64 KB partials + wred (disjoint)
    float* stage = lds;                      // [1024]: 0..511 f, 512..1023 colq
    float* wred  = lds + 16384;              // [16] wave partials for s

    int tid   = threadIdx.x;
    int blk   = blockIdx.x;
    int b     = blk >> 4;            // batch
    int g     = blk & 15;            // row-group: rows g*32..g*32+31
    int w     = tid >> 6;            // wave 0..15
    int lane  = tid & 63;
    int r_loc = tid >> 5;            // 0..31 local row
    int cseg  = tid & 31;            // owns cols cseg + 32k
    int j     = g * 32 + r_loc;

    const float lr = lrbuf[b];
    size_t rowbase = ((size_t)b * NN + j) * MM;

    float q[16], x[16], fk[16];
    #pragma unroll
    for (int k = 0; k < 16; ++k) q[k] = qm[rowbase + cseg + 32*k];

    const float inv_m = 1.0f / (float)MM;
    #pragma unroll
    for (int k = 0; k < 16; ++k) { x[k] = inv_m; fk[k] = 1.0f; }

    float s = s1buf[b];
    unsigned* myflag = flags + b * 32 + g;
    unsigned* bflags = flags + b * 32;

    for (int t = 1; t <= QP_ITERS; ++t) {
        if (t > 1) {
            // ---- gather prev iteration's partials (parity (t-1)&1) ----
            const float* p = part + (size_t)((t - 1) & 1) * (NBLK * SLOT)
                           + (size_t)b * (16 * SLOT) + tid;
            float acc = 0.f;
            #pragma unroll
            for (int g2 = 0; g2 < 16; ++g2)
                acc += __hip_atomic_load((float*)(p + g2 * SLOT),
                                         __ATOMIC_RELAXED,
                                         __HIP_MEMORY_SCOPE_AGENT);
            if (tid < 512) stage[tid] = fminf(1.0f, 2.0f / (acc + 1e-8f)); // f
            else           stage[tid] = acc;                               // colq
            __syncthreads();
            float v = (tid < 512) ? stage[tid] * stage[512 + tid] : 0.f;
            #pragma unroll
            for (int m = 32; m; m >>= 1) v += __shfl_xor(v, m);
            if (lane == 0) wred[w] = v;
            #pragma unroll
            for (int k = 0; k < 16; ++k) fk[k] = stage[cseg + 32*k];
            __syncthreads();
            float sacc = 0.f;
            #pragma unroll
            for (int i = 0; i < 16; ++i) sacc += wred[i];   // LDS broadcast
            s = sacc;
        }

        // ---- gradient step + clip + row normalize ----
        float c = 2.0f * lr * s;
        float rp = 0.f;
        #pragma unroll
        for (int k = 0; k < 16; ++k) {
            float v = x[k] * fk[k] - c * q[k];
            v = fminf(fmaxf(v, 0.f), 1.f);
            x[k] = v;
            rp += v;
        }
        #pragma unroll
        for (int m = 16; m; m >>= 1) rp += __shfl_xor(rp, m);
        float inv = 1.0f / (rp + 1e-8f);
        #pragma unroll
        for (int k = 0; k < 16; ++k) x[k] *= inv;

        // ---- column partial pass (wred is disjoint; no extra barrier) ----
        __syncthreads();   // all threads done reading stage before overwrite
        #pragma unroll
        for (int k = 0; k < 16; ++k) {
            float qx = q[k] * x[k];
            float px = x[k] + __shfl_xor(x[k], 32);   // row-pair sum
            float pq = qx   + __shfl_xor(qx,   32);
            int col = cseg + 32*k;
            if (lane < 32) lds[w * 512 + col]        = px;   // x partials
            else           lds[8192 + w * 512 + col] = pq;   // qx partials
        }
        __syncthreads();
        {
            int arr = tid >> 9;          // 0 => colsum(x), 1 => colsum(qx)
            int col = tid & 511;
            const float* basep = lds + arr * 8192 + col;
            float acc = 0.f;
            #pragma unroll
            for (int w2 = 0; w2 < 16; ++w2) acc += basep[w2 * 512];
            float* dst = part + (size_t)(t & 1) * (NBLK * SLOT)
                       + (size_t)blk * SLOT + tid;
            __hip_atomic_store(dst, acc, __ATOMIC_RELAXED,
                               __HIP_MEMORY_SCOPE_AGENT);
        }

        // ---- per-batch flag sync (no RMW) ----
        __syncthreads();   // drain every thread's partial store (vmcnt 0)
        if (tid == 0)
            __hip_atomic_store(myflag, (unsigned)t, __ATOMIC_RELEASE,
                               __HIP_MEMORY_SCOPE_AGENT);
        if (w == 0) {
            for (;;) {
                unsigned v = (lane < 16)
                    ? __hip_atomic_load(bflags + lane, __ATOMIC_ACQUIRE,
                                        __HIP_MEMORY_SCOPE_AGENT)
                    : (unsigned)t;
                if (__all(v >= (unsigned)t)) break;
            }
        }
        __syncthreads();
    }

    // ---- final lazy column scale from iteration 20's colsum ----
    {
        const float* p = part + (size_t)(QP_ITERS & 1) * (NBLK * SLOT)
                       + (size_t)b * (16 * SLOT) + tid;   // tid<512: x-partials
        if (tid < 512) {
            float acc = 0.f;
            #pragma unroll
            for (int g2 = 0; g2 < 16; ++g2)
                acc += __hip_atomic_load((float*)(p + g2 * SLOT),
                                         __ATOMIC_RELAXED,
                                         __HIP_MEMORY_SCOPE_AGENT);
            stage[tid] = fminf(1.0f, 2.0f / (acc + 1e-8f));
        }
        __syncthreads();
        #pragma unroll
        for (int k = 0; k < 16; ++k)
            out[rowbase + cseg + 32*k] = x[k] * stage[cseg + 32*k];
    }
}

// ---------------------------------------------------------------------------
extern "C" void kernel_launch(void* const* d_in, const int* in_sizes, int n_in,
                              void* d_out, int out_size, void* d_ws, size_t ws_size,
                              hipStream_t stream)
{
    const float* nc = (const float*)d_in[0];  // n_emb_cur (16,512,128)
    const float* ec = (const float*)d_in[1];  // e_emb_cur
    const float* nn = (const float*)d_in[2];  // n_emb_nxt
    const float* en = (const float*)d_in[3];  // e_emb_nxt
    float* out = (float*)d_out;               // (16, 512*512) fp32

    float* ws = (float*)d_ws;
    const size_t QM_FLOATS = (size_t)BATCH * NN * MM;       // 4,194,304

    float* qm   = ws;
    float* part = ws + QM_FLOATS;                           // 2*NBLK*SLOT floats
    // contiguous zero region: sumq, sumq2, flags
    float* zreg  = part + (size_t)2 * NBLK * SLOT;
    float* sumq  = zreg;                                    // 16
    float* sumq2 = zreg + 16;                               // 16
    unsigned* flags = (unsigned*)(zreg + 32);               // 16*32 words
    const int ZN = 32 + BATCH * 32;                         // 544
    float* rc    = zreg + 576;                              // 8192
    float* rn    = rc + BATCH * MM;                         // 8192
    float* lrbuf = rn + BATCH * NN;                         // 16
    float* s1buf = lrbuf + 16;                              // 16

    zero_ws_kernel<<<3, 256, 0, stream>>>(zreg, ZN);
    row_norms_kernel<<<BATCH * 512, 64, 0, stream>>>(nc, ec, nn, en, rc, rn);
    gemm_q_kernel<<<dim3(4, 4, BATCH), 256, 0, stream>>>(nc, ec, nn, en, rc, rn,
                                                         qm, sumq, sumq2);
    init_scalars_kernel<<<1, 64, 0, stream>>>(sumq, sumq2, lrbuf, s1buf);

    void* args[] = { (void*)&qm, (void*)&lrbuf, (void*)&s1buf,
                     (void*)&part, (void*)&flags, (void*)&out };
    hipLaunchCooperativeKernel((const void*)qp_iter_kernel,
                               dim3(NBLK), dim3(1024),
                               args, 0, stream);
}

// Round 9
// 363.096 us; speedup vs baseline: 1.7454x; 1.0508x over previous
//
#include <hip/hip_runtime.h>

#define BATCH 16
#define NN 512   // n  (j index, "nxt" side; rows of X)
#define MM 512   // m  (i index, "cur" side; cols of X)
#define DD 128
#define QP_ITERS 20
#define NBLK (BATCH * 16)   // 256 qp blocks, 1 per CU
#define SLOT 1024           // floats per block slot (512 x-partials + 512 qx)
#define ZFLOATS (32 + 512)  // sumq(16) + sumq2(16) + flags(512)

// ---------------------------------------------------------------------------
// row_norms (+ fused workspace zeroing in first 9 blocks):
//   rc[b*512+p] = ||nc[b,p]||^2 + ||ec[b,p]||^2
//   rn[b*512+p] = ||nn[b,p]||^2 + ||en[b,p]||^2
// ---------------------------------------------------------------------------
__global__ __launch_bounds__(64) void row_norms_kernel(
    const float* __restrict__ nc, const float* __restrict__ ec,
    const float* __restrict__ nn, const float* __restrict__ en,
    float* __restrict__ rc, float* __restrict__ rn, float* __restrict__ zreg)
{
    int row = blockIdx.x;            // b*512 + p
    int t   = threadIdx.x;           // 0..63

    if (blockIdx.x < 9) {            // fused zero of sumq/sumq2/flags
        int z = blockIdx.x * 64 + t;
        if (z < ZFLOATS) zreg[z] = 0.f;
    }

    size_t base = (size_t)row * DD;

    float2 a = ((const float2*)(nc + base))[t];
    float2 b = ((const float2*)(ec + base))[t];
    float vc = a.x*a.x + a.y*a.y + b.x*b.x + b.y*b.y;

    float2 c = ((const float2*)(nn + base))[t];
    float2 d = ((const float2*)(en + base))[t];
    float vn = c.x*c.x + c.y*c.y + d.x*d.x + d.y*d.y;

    #pragma unroll
    for (int off = 32; off; off >>= 1) {
        vc += __shfl_down(vc, off);
        vn += __shfl_down(vn, off);
    }
    if (t == 0) { rc[row] = vc; rn[row] = vn; }
}

// ---------------------------------------------------------------------------
// gemm_q v2 (proven R7): 128x128 tile, 8x8 micro, K=256 concat, k-major LDS,
// register-prefetch double buffering. + per-batch sum/sum2 atomics.
// ---------------------------------------------------------------------------
__global__ __launch_bounds__(256, 1) void gemm_q_kernel(
    const float* __restrict__ nc, const float* __restrict__ ec,
    const float* __restrict__ nn, const float* __restrict__ en,
    const float* __restrict__ rc, const float* __restrict__ rn,
    float* __restrict__ qm, float* __restrict__ sumq, float* __restrict__ sumq2)
{
    int b  = blockIdx.z;
    int it = blockIdx.x;
    int jt = blockIdx.y;
    int tid = threadIdx.x;
    int tx = tid & 15, ty = tid >> 4;

    __shared__ float As[8][128];
    __shared__ float Bs[8][128];

    float acc[8][8] = {};

    int srow = tid & 127;
    int sk4  = (tid >> 7) * 4;

    const float* aBase[2] = { nn + ((size_t)b*NN + jt*128) * DD,
                              en + ((size_t)b*NN + jt*128) * DD };
    const float* bBase[2] = { nc + ((size_t)b*MM + it*128) * DD,
                              ec + ((size_t)b*MM + it*128) * DD };

    float4 pa = *(const float4*)(aBase[0] + (size_t)srow * DD + sk4);
    float4 pb = *(const float4*)(bBase[0] + (size_t)srow * DD + sk4);

    for (int stage = 0; stage < 32; ++stage) {
        __syncthreads();
        As[sk4+0][srow] = pa.x; As[sk4+1][srow] = pa.y;
        As[sk4+2][srow] = pa.z; As[sk4+3][srow] = pa.w;
        Bs[sk4+0][srow] = pb.x; Bs[sk4+1][srow] = pb.y;
        Bs[sk4+2][srow] = pb.z; Bs[sk4+3][srow] = pb.w;
        __syncthreads();

        if (stage + 1 < 32) {
            int s   = stage + 1;
            int mat = s >> 4;
            int kc  = (s & 15) * 8;
            pa = *(const float4*)(aBase[mat] + (size_t)srow * DD + kc + sk4);
            pb = *(const float4*)(bBase[mat] + (size_t)srow * DD + kc + sk4);
        }

        #pragma unroll
        for (int k = 0; k < 8; ++k) {
            float af[8], bf[8];
            *(float4*)&af[0] = *(const float4*)&As[k][ty*8];
            *(float4*)&af[4] = *(const float4*)&As[k][ty*8+4];
            *(float4*)&bf[0] = *(const float4*)&Bs[k][tx*8];
            *(float4*)&bf[4] = *(const float4*)&Bs[k][tx*8+4];
            #pragma unroll
            for (int r = 0; r < 8; ++r)
                #pragma unroll
                for (int c = 0; c < 8; ++c)
                    acc[r][c] += af[r] * bf[c];
        }
    }

    float rci[8];
    int i0 = it*128 + tx*8;
    #pragma unroll
    for (int c = 0; c < 8; ++c) rci[c] = rc[b*MM + i0 + c];

    float qs = 0.f, q2s = 0.f;
    #pragma unroll
    for (int r = 0; r < 8; ++r) {
        int j = jt*128 + ty*8 + r;
        float rnj = rn[b*NN + j];
        size_t rowp = ((size_t)b*NN + j)*MM + i0;
        float4 o0, o1;
        float v;
        v = 0.5f*(rci[0] + rnj) - acc[r][0]; o0.x = v; qs += v; q2s += v*v;
        v = 0.5f*(rci[1] + rnj) - acc[r][1]; o0.y = v; qs += v; q2s += v*v;
        v = 0.5f*(rci[2] + rnj) - acc[r][2]; o0.z = v; qs += v; q2s += v*v;
        v = 0.5f*(rci[3] + rnj) - acc[r][3]; o0.w = v; qs += v; q2s += v*v;
        v = 0.5f*(rci[4] + rnj) - acc[r][4]; o1.x = v; qs += v; q2s += v*v;
        v = 0.5f*(rci[5] + rnj) - acc[r][5]; o1.y = v; qs += v; q2s += v*v;
        v = 0.5f*(rci[6] + rnj) - acc[r][6]; o1.z = v; qs += v; q2s += v*v;
        v = 0.5f*(rci[7] + rnj) - acc[r][7]; o1.w = v; qs += v; q2s += v*v;
        *(float4*)(qm + rowp)     = o0;
        *(float4*)(qm + rowp + 4) = o1;
    }

    #pragma unroll
    for (int off = 32; off; off >>= 1) {
        qs  += __shfl_down(qs,  off);
        q2s += __shfl_down(q2s, off);
    }
    __shared__ float red[8];
    int wid = tid >> 6, lane = tid & 63;
    if (lane == 0) { red[wid] = qs; red[4 + wid] = q2s; }
    __syncthreads();
    if (tid == 0) {
        atomicAdd(&sumq[b],  red[0] + red[1] + red[2] + red[3]);
        atomicAdd(&sumq2[b], red[4] + red[5] + red[6] + red[7]);
    }
}

// ---------------------------------------------------------------------------
__device__ __forceinline__ float gather16_sum_agent(const float* p)
{
    float acc = 0.f;
    #pragma unroll
    for (int g2 = 0; g2 < 16; ++g2)
        acc += __hip_atomic_load((float*)(p + g2 * SLOT), __ATOMIC_RELAXED,
                                 __HIP_MEMORY_SCOPE_AGENT);
    return acc;
}

// ---------------------------------------------------------------------------
// qp_iter_kernel v7: persistent 20-iteration PGD solve (R5/R7-proven memory
// pattern). 256 blocks x 1024 threads; qm and X register-resident (16
// elems/thread, strided columns i = cseg + 32k). Per-batch RMW-free flag
// sync with SPECULATIVE probe-gather: wave0 acquire-probes the 16 flags
// once; if already set, the poll round-trip is skipped entirely; otherwise
// fall back to the proven poll + re-gather. lr/s1 computed in-prologue from
// gemm's sumq/sumq2 (init kernel folded away).
// ---------------------------------------------------------------------------
__global__ __launch_bounds__(1024, 4) void qp_iter_kernel(
    const float* __restrict__ qm, const float* __restrict__ sumq,
    const float* __restrict__ sumq2, float* __restrict__ part,
    unsigned* __restrict__ flags, float* __restrict__ out)
{
    __shared__ float lds[16384 + 32];        // partial matrices + wred
    __shared__ int sh_ok;
    float* stage = lds;                      // [1024]: 0..511 f, 512..1023 colq
    float* wred  = lds + 16384;              // [16] wave partials for s

    int tid   = threadIdx.x;
    int blk   = blockIdx.x;
    int b     = blk >> 4;            // batch
    int g     = blk & 15;            // row-group: rows g*32..g*32+31
    int w     = tid >> 6;            // wave 0..15
    int lane  = tid & 63;
    int r_loc = tid >> 5;            // 0..31 local row
    int cseg  = tid & 31;            // owns cols cseg + 32k
    int j     = g * 32 + r_loc;

    const float lr = 0.5f / (sumq2[b] + 1e-8f);
    size_t rowbase = ((size_t)b * NN + j) * MM;

    float q[16], x[16], fk[16];
    #pragma unroll
    for (int k = 0; k < 16; ++k) q[k] = qm[rowbase + cseg + 32*k];

    const float inv_m = 1.0f / (float)MM;
    #pragma unroll
    for (int k = 0; k < 16; ++k) { x[k] = inv_m; fk[k] = 1.0f; }

    float s = sumq[b] * inv_m;       // s1 = sum(qm)/m  (X0 = 1/m)
    unsigned* myflag = flags + b * 32 + g;
    unsigned* bflags = flags + b * 32;

    for (int t = 1; t <= QP_ITERS; ++t) {
        if (t > 1) {
            unsigned tt = (unsigned)(t - 1);
            // ---- speculative probe (acquire) ----
            if (w == 0) {
                unsigned v = (lane < 16)
                    ? __hip_atomic_load(bflags + lane, __ATOMIC_ACQUIRE,
                                        __HIP_MEMORY_SCOPE_AGENT)
                    : tt;
                int ok = __all(v >= tt);
                if (lane == 0) sh_ok = ok;
            }
            __syncthreads();   // broadcast sh_ok; prior lds reads all done

            const float* p = part + (size_t)((t - 1) & 1) * (NBLK * SLOT)
                           + (size_t)b * (16 * SLOT) + tid;
            float acc = gather16_sum_agent(p);

            if (!sh_ok) {      // fallback: proven poll + ordered re-gather
                if (w == 0) {
                    for (;;) {
                        unsigned v = (lane < 16)
                            ? __hip_atomic_load(bflags + lane, __ATOMIC_ACQUIRE,
                                                __HIP_MEMORY_SCOPE_AGENT)
                            : tt;
                        if (__all(v >= tt)) break;
                    }
                }
                __syncthreads();
                acc = gather16_sum_agent(p);
            }

            if (tid < 512) stage[tid] = fminf(1.0f, 2.0f / (acc + 1e-8f)); // f
            else           stage[tid] = acc;                               // colq
            __syncthreads();
            float v = (tid < 512) ? stage[tid] * stage[512 + tid] : 0.f;
            #pragma unroll
            for (int m = 32; m; m >>= 1) v += __shfl_xor(v, m);
            if (lane == 0) wred[w] = v;
            #pragma unroll
            for (int k = 0; k < 16; ++k) fk[k] = stage[cseg + 32*k];
            __syncthreads();   // wred ready; all stage reads complete
            float sacc = 0.f;
            #pragma unroll
            for (int i = 0; i < 16; ++i) sacc += wred[i];   // LDS broadcast
            s = sacc;
        }

        // ---- gradient step + clip + row normalize ----
        float c = 2.0f * lr * s;
        float rp = 0.f;
        #pragma unroll
        for (int k = 0; k < 16; ++k) {
            float v = x[k] * fk[k] - c * q[k];
            v = fminf(fmaxf(v, 0.f), 1.f);
            x[k] = v;
            rp += v;
        }
        #pragma unroll
        for (int m = 16; m; m >>= 1) rp += __shfl_xor(rp, m);
        float inv = 1.0f / (rp + 1e-8f);
        #pragma unroll
        for (int k = 0; k < 16; ++k) x[k] *= inv;

        // ---- column partial pass (stage reads finished before wred barrier;
        //      at t==1 lds is untouched — no extra barrier needed) ----
        #pragma unroll
        for (int k = 0; k < 16; ++k) {
            float qx = q[k] * x[k];
            float px = x[k] + __shfl_xor(x[k], 32);   // row-pair sum
            float pq = qx   + __shfl_xor(qx,   32);
            int col = cseg + 32*k;
            if (lane < 32) lds[w * 512 + col]        = px;   // x partials
            else           lds[8192 + w * 512 + col] = pq;   // qx partials
        }
        __syncthreads();
        {
            int arr = tid >> 9;          // 0 => colsum(x), 1 => colsum(qx)
            int col = tid & 511;
            const float* basep = lds + arr * 8192 + col;
            float acc = 0.f;
            #pragma unroll
            for (int w2 = 0; w2 < 16; ++w2) acc += basep[w2 * 512];
            float* dst = part + (size_t)(t & 1) * (NBLK * SLOT)
                       + (size_t)blk * SLOT + tid;
            __hip_atomic_store(dst, acc, __ATOMIC_RELAXED,
                               __HIP_MEMORY_SCOPE_AGENT);
        }

        __syncthreads();   // drain every thread's partial store (vmcnt 0)
        if (tid == 0)
            __hip_atomic_store(myflag, (unsigned)t, __ATOMIC_RELEASE,
                               __HIP_MEMORY_SCOPE_AGENT);
    }

    // ---- final: poll iteration 20's flags, gather colsum, scale, store ----
    {
        unsigned tt = (unsigned)QP_ITERS;
        if (w == 0) {
            for (;;) {
                unsigned v = (lane < 16)
                    ? __hip_atomic_load(bflags + lane, __ATOMIC_ACQUIRE,
                                        __HIP_MEMORY_SCOPE_AGENT)
                    : tt;
                if (__all(v >= tt)) break;
            }
        }
        __syncthreads();
        const float* p = part + (size_t)(QP_ITERS & 1) * (NBLK * SLOT)
                       + (size_t)b * (16 * SLOT) + tid;   // tid<512: x-partials
        if (tid < 512) {
            float acc = gather16_sum_agent(p);
            stage[tid] = fminf(1.0f, 2.0f / (acc + 1e-8f));
        }
        __syncthreads();
        #pragma unroll
        for (int k = 0; k < 16; ++k)
            out[rowbase + cseg + 32*k] = x[k] * stage[cseg + 32*k];
    }
}

// ---------------------------------------------------------------------------
extern "C" void kernel_launch(void* const* d_in, const int* in_sizes, int n_in,
                              void* d_out, int out_size, void* d_ws, size_t ws_size,
                              hipStream_t stream)
{
    const float* nc = (const float*)d_in[0];  // n_emb_cur (16,512,128)
    const float* ec = (const float*)d_in[1];  // e_emb_cur
    const float* nn = (const float*)d_in[2];  // n_emb_nxt
    const float* en = (const float*)d_in[3];  // e_emb_nxt
    float* out = (float*)d_out;               // (16, 512*512) fp32

    float* ws = (float*)d_ws;
    const size_t QM_FLOATS = (size_t)BATCH * NN * MM;       // 4,194,304

    float* qm   = ws;
    float* part = ws + QM_FLOATS;                           // 2*NBLK*SLOT floats
    // zero region (cleared by row_norms blocks 0-8): sumq, sumq2, flags
    float* zreg  = part + (size_t)2 * NBLK * SLOT;
    float* sumq  = zreg;                                    // 16
    float* sumq2 = zreg + 16;                               // 16
    unsigned* flags = (unsigned*)(zreg + 32);               // 512
    float* rc    = zreg + ZFLOATS;                          // 8192
    float* rn    = rc + BATCH * MM;                         // 8192

    row_norms_kernel<<<BATCH * 512, 64, 0, stream>>>(nc, ec, nn, en, rc, rn, zreg);
    gemm_q_kernel<<<dim3(4, 4, BATCH), 256, 0, stream>>>(nc, ec, nn, en, rc, rn,
                                                         qm, sumq, sumq2);

    void* args[] = { (void*)&qm, (void*)&sumq, (void*)&sumq2,
                     (void*)&part, (void*)&flags, (void*)&out };
    hipLaunchCooperativeKernel((const void*)qp_iter_kernel,
                               dim3(NBLK), dim3(1024),
                               args, 0, stream);
}

// Round 10
// 355.187 us; speedup vs baseline: 1.7842x; 1.0223x over previous
//
#include <hip/hip_runtime.h>

#define BATCH 16
#define NN 512   // n  (j index, "nxt" side; rows of X)
#define MM 512   // m  (i index, "cur" side; cols of X)
#define DD 128
#define QP_ITERS 20
#define NBLK (BATCH * 16)   // 256 qp blocks, 1 per CU
#define SLOT 1024           // floats per block slot (512 x-partials + 512 qx)
#define ZFLOATS (32 + 512)  // sumq(16) + sumq2(16) + flags(512)

// ---------------------------------------------------------------------------
// row_norms (+ fused workspace zeroing in first 9 blocks):
//   rc[b*512+p] = ||nc[b,p]||^2 + ||ec[b,p]||^2
//   rn[b*512+p] = ||nn[b,p]||^2 + ||en[b,p]||^2
// ---------------------------------------------------------------------------
__global__ __launch_bounds__(64) void row_norms_kernel(
    const float* __restrict__ nc, const float* __restrict__ ec,
    const float* __restrict__ nn, const float* __restrict__ en,
    float* __restrict__ rc, float* __restrict__ rn, float* __restrict__ zreg)
{
    int row = blockIdx.x;            // b*512 + p
    int t   = threadIdx.x;           // 0..63

    if (blockIdx.x < 9) {            // fused zero of sumq/sumq2/flags
        int z = blockIdx.x * 64 + t;
        if (z < ZFLOATS) zreg[z] = 0.f;
    }

    size_t base = (size_t)row * DD;

    float2 a = ((const float2*)(nc + base))[t];
    float2 b = ((const float2*)(ec + base))[t];
    float vc = a.x*a.x + a.y*a.y + b.x*b.x + b.y*b.y;

    float2 c = ((const float2*)(nn + base))[t];
    float2 d = ((const float2*)(en + base))[t];
    float vn = c.x*c.x + c.y*c.y + d.x*d.x + d.y*d.y;

    #pragma unroll
    for (int off = 32; off; off >>= 1) {
        vc += __shfl_down(vc, off);
        vn += __shfl_down(vn, off);
    }
    if (t == 0) { rc[row] = vc; rn[row] = vn; }
}

// ---------------------------------------------------------------------------
// gemm_q v3: qm[b,j,i] = 0.5*(rc[b,i]+rn[b,j]) - (nc_i.nn_j + ec_i.en_j)
// 128(i) x 64(j) tile, BK=16, 512 blocks (2/CU, __launch_bounds__(256,2)),
// k-major LDS, 4x8 micro-tile, register-prefetch double buffering.
// ---------------------------------------------------------------------------
__global__ __launch_bounds__(256, 2) void gemm_q_kernel(
    const float* __restrict__ nc, const float* __restrict__ ec,
    const float* __restrict__ nn, const float* __restrict__ en,
    const float* __restrict__ rc, const float* __restrict__ rn,
    float* __restrict__ qm, float* __restrict__ sumq, float* __restrict__ sumq2)
{
    int b  = blockIdx.z;
    int it = blockIdx.x;             // i tile, 128 wide (0..3)
    int jt = blockIdx.y;             // j tile,  64 wide (0..7)
    int tid = threadIdx.x;
    int tx = tid & 15, ty = tid >> 4;   // micro: 8 i-cols x 4 j-rows

    __shared__ float As[16][64];     // k-major, j rows   (4 KB)
    __shared__ float Bs[16][128];    // k-major, i rows   (8 KB)

    float acc[4][8] = {};            // [j][i]

    // staging assignment
    int a_row = tid & 63;            // A: 64 rows x 16k -> 1 float4/thread
    int a_kc  = (tid >> 6) * 4;      // 0,4,8,12
    int b_row = tid & 127;           // B: 128 rows x 16k -> 2 float4/thread
    int b_kc  = (tid >> 7) * 8;      // 0 or 8

    const float* aBase[2] = { nn + ((size_t)b*NN + jt*64)  * DD,
                              en + ((size_t)b*NN + jt*64)  * DD };
    const float* bBase[2] = { nc + ((size_t)b*MM + it*128) * DD,
                              ec + ((size_t)b*MM + it*128) * DD };

    // prefetch stage 0 (mat 0, kb 0)
    float4 pa  = *(const float4*)(aBase[0] + (size_t)a_row * DD + a_kc);
    float4 pb0 = *(const float4*)(bBase[0] + (size_t)b_row * DD + b_kc);
    float4 pb1 = *(const float4*)(bBase[0] + (size_t)b_row * DD + b_kc + 4);

    for (int stage = 0; stage < 16; ++stage) {
        __syncthreads();             // prior stage's LDS reads complete
        As[a_kc+0][a_row] = pa.x;  As[a_kc+1][a_row] = pa.y;
        As[a_kc+2][a_row] = pa.z;  As[a_kc+3][a_row] = pa.w;
        Bs[b_kc+0][b_row] = pb0.x; Bs[b_kc+1][b_row] = pb0.y;
        Bs[b_kc+2][b_row] = pb0.z; Bs[b_kc+3][b_row] = pb0.w;
        Bs[b_kc+4][b_row] = pb1.x; Bs[b_kc+5][b_row] = pb1.y;
        Bs[b_kc+6][b_row] = pb1.z; Bs[b_kc+7][b_row] = pb1.w;
        __syncthreads();

        if (stage + 1 < 16) {        // prefetch next stage while computing
            int s   = stage + 1;
            int mat = s >> 3;
            int kb  = (s & 7) * 16;
            pa  = *(const float4*)(aBase[mat] + (size_t)a_row * DD + kb + a_kc);
            pb0 = *(const float4*)(bBase[mat] + (size_t)b_row * DD + kb + b_kc);
            pb1 = *(const float4*)(bBase[mat] + (size_t)b_row * DD + kb + b_kc + 4);
        }

        #pragma unroll
        for (int k = 0; k < 16; ++k) {
            float af[4], bf[8];
            *(float4*)&af[0] = *(const float4*)&As[k][ty*4];
            *(float4*)&bf[0] = *(const float4*)&Bs[k][tx*8];
            *(float4*)&bf[4] = *(const float4*)&Bs[k][tx*8+4];
            #pragma unroll
            for (int r = 0; r < 4; ++r)
                #pragma unroll
                for (int c = 0; c < 8; ++c)
                    acc[r][c] += af[r] * bf[c];
        }
    }

    // epilogue: qm = 0.5*(rc_i + rn_j) - dot, + sum / sum-of-squares
    float rci[8];
    int i0 = it*128 + tx*8;
    #pragma unroll
    for (int c = 0; c < 8; ++c) rci[c] = rc[b*MM + i0 + c];

    float qs = 0.f, q2s = 0.f;
    #pragma unroll
    for (int r = 0; r < 4; ++r) {
        int j = jt*64 + ty*4 + r;
        float rnj = rn[b*NN + j];
        size_t rowp = ((size_t)b*NN + j)*MM + i0;
        float4 o0, o1;
        float v;
        v = 0.5f*(rci[0] + rnj) - acc[r][0]; o0.x = v; qs += v; q2s += v*v;
        v = 0.5f*(rci[1] + rnj) - acc[r][1]; o0.y = v; qs += v; q2s += v*v;
        v = 0.5f*(rci[2] + rnj) - acc[r][2]; o0.z = v; qs += v; q2s += v*v;
        v = 0.5f*(rci[3] + rnj) - acc[r][3]; o0.w = v; qs += v; q2s += v*v;
        v = 0.5f*(rci[4] + rnj) - acc[r][4]; o1.x = v; qs += v; q2s += v*v;
        v = 0.5f*(rci[5] + rnj) - acc[r][5]; o1.y = v; qs += v; q2s += v*v;
        v = 0.5f*(rci[6] + rnj) - acc[r][6]; o1.z = v; qs += v; q2s += v*v;
        v = 0.5f*(rci[7] + rnj) - acc[r][7]; o1.w = v; qs += v; q2s += v*v;
        *(float4*)(qm + rowp)     = o0;
        *(float4*)(qm + rowp + 4) = o1;
    }

    #pragma unroll
    for (int off = 32; off; off >>= 1) {
        qs  += __shfl_down(qs,  off);
        q2s += __shfl_down(q2s, off);
    }
    __shared__ float red[8];
    int wid = tid >> 6, lane = tid & 63;
    if (lane == 0) { red[wid] = qs; red[4 + wid] = q2s; }
    __syncthreads();
    if (tid == 0) {
        atomicAdd(&sumq[b],  red[0] + red[1] + red[2] + red[3]);
        atomicAdd(&sumq2[b], red[4] + red[5] + red[6] + red[7]);
    }
}

// ---------------------------------------------------------------------------
__device__ __forceinline__ float gather16_sum_agent(const float* p)
{
    float acc = 0.f;
    #pragma unroll
    for (int g2 = 0; g2 < 16; ++g2)
        acc += __hip_atomic_load((float*)(p + g2 * SLOT), __ATOMIC_RELAXED,
                                 __HIP_MEMORY_SCOPE_AGENT);
    return acc;
}

// ---------------------------------------------------------------------------
// qp_iter_kernel (R9-proven, unchanged): persistent 20-iteration PGD solve.
// 256 blocks x 1024 threads; qm and X register-resident. Per-batch RMW-free
// flag sync with speculative probe-gather + proven poll fallback.
// ---------------------------------------------------------------------------
__global__ __launch_bounds__(1024, 4) void qp_iter_kernel(
    const float* __restrict__ qm, const float* __restrict__ sumq,
    const float* __restrict__ sumq2, float* __restrict__ part,
    unsigned* __restrict__ flags, float* __restrict__ out)
{
    __shared__ float lds[16384 + 32];        // partial matrices + wred
    __shared__ int sh_ok;
    float* stage = lds;                      // [1024]: 0..511 f, 512..1023 colq
    float* wred  = lds + 16384;              // [16] wave partials for s

    int tid   = threadIdx.x;
    int blk   = blockIdx.x;
    int b     = blk >> 4;            // batch
    int g     = blk & 15;            // row-group: rows g*32..g*32+31
    int w     = tid >> 6;            // wave 0..15
    int lane  = tid & 63;
    int r_loc = tid >> 5;            // 0..31 local row
    int cseg  = tid & 31;            // owns cols cseg + 32k
    int j     = g * 32 + r_loc;

    const float lr = 0.5f / (sumq2[b] + 1e-8f);
    size_t rowbase = ((size_t)b * NN + j) * MM;

    float q[16], x[16], fk[16];
    #pragma unroll
    for (int k = 0; k < 16; ++k) q[k] = qm[rowbase + cseg + 32*k];

    const float inv_m = 1.0f / (float)MM;
    #pragma unroll
    for (int k = 0; k < 16; ++k) { x[k] = inv_m; fk[k] = 1.0f; }

    float s = sumq[b] * inv_m;       // s1 = sum(qm)/m  (X0 = 1/m)
    unsigned* myflag = flags + b * 32 + g;
    unsigned* bflags = flags + b * 32;

    for (int t = 1; t <= QP_ITERS; ++t) {
        if (t > 1) {
            unsigned tt = (unsigned)(t - 1);
            // ---- speculative probe (acquire) ----
            if (w == 0) {
                unsigned v = (lane < 16)
                    ? __hip_atomic_load(bflags + lane, __ATOMIC_ACQUIRE,
                                        __HIP_MEMORY_SCOPE_AGENT)
                    : tt;
                int ok = __all(v >= tt);
                if (lane == 0) sh_ok = ok;
            }
            __syncthreads();   // broadcast sh_ok; prior lds reads all done

            const float* p = part + (size_t)((t - 1) & 1) * (NBLK * SLOT)
                           + (size_t)b * (16 * SLOT) + tid;
            float acc = gather16_sum_agent(p);

            if (!sh_ok) {      // fallback: proven poll + ordered re-gather
                if (w == 0) {
                    for (;;) {
                        unsigned v = (lane < 16)
                            ? __hip_atomic_load(bflags + lane, __ATOMIC_ACQUIRE,
                                                __HIP_MEMORY_SCOPE_AGENT)
                            : tt;
                        if (__all(v >= tt)) break;
                    }
                }
                __syncthreads();
                acc = gather16_sum_agent(p);
            }

            if (tid < 512) stage[tid] = fminf(1.0f, 2.0f / (acc + 1e-8f)); // f
            else           stage[tid] = acc;                               // colq
            __syncthreads();
            float v = (tid < 512) ? stage[tid] * stage[512 + tid] : 0.f;
            #pragma unroll
            for (int m = 32; m; m >>= 1) v += __shfl_xor(v, m);
            if (lane == 0) wred[w] = v;
            #pragma unroll
            for (int k = 0; k < 16; ++k) fk[k] = stage[cseg + 32*k];
            __syncthreads();   // wred ready; all stage reads complete
            float sacc = 0.f;
            #pragma unroll
            for (int i = 0; i < 16; ++i) sacc += wred[i];   // LDS broadcast
            s = sacc;
        }

        // ---- gradient step + clip + row normalize ----
        float c = 2.0f * lr * s;
        float rp = 0.f;
        #pragma unroll
        for (int k = 0; k < 16; ++k) {
            float v = x[k] * fk[k] - c * q[k];
            v = fminf(fmaxf(v, 0.f), 1.f);
            x[k] = v;
            rp += v;
        }
        #pragma unroll
        for (int m = 16; m; m >>= 1) rp += __shfl_xor(rp, m);
        float inv = 1.0f / (rp + 1e-8f);
        #pragma unroll
        for (int k = 0; k < 16; ++k) x[k] *= inv;

        // ---- column partial pass ----
        #pragma unroll
        for (int k = 0; k < 16; ++k) {
            float qx = q[k] * x[k];
            float px = x[k] + __shfl_xor(x[k], 32);   // row-pair sum
            float pq = qx   + __shfl_xor(qx,   32);
            int col = cseg + 32*k;
            if (lane < 32) lds[w * 512 + col]        = px;   // x partials
            else           lds[8192 + w * 512 + col] = pq;   // qx partials
        }
        __syncthreads();
        {
            int arr = tid >> 9;          // 0 => colsum(x), 1 => colsum(qx)
            int col = tid & 511;
            const float* basep = lds + arr * 8192 + col;
            float acc = 0.f;
            #pragma unroll
            for (int w2 = 0; w2 < 16; ++w2) acc += basep[w2 * 512];
            float* dst = part + (size_t)(t & 1) * (NBLK * SLOT)
                       + (size_t)blk * SLOT + tid;
            __hip_atomic_store(dst, acc, __ATOMIC_RELAXED,
                               __HIP_MEMORY_SCOPE_AGENT);
        }

        __syncthreads();   // drain every thread's partial store (vmcnt 0)
        if (tid == 0)
            __hip_atomic_store(myflag, (unsigned)t, __ATOMIC_RELEASE,
                               __HIP_MEMORY_SCOPE_AGENT);
    }

    // ---- final: poll iteration 20's flags, gather colsum, scale, store ----
    {
        unsigned tt = (unsigned)QP_ITERS;
        if (w == 0) {
            for (;;) {
                unsigned v = (lane < 16)
                    ? __hip_atomic_load(bflags + lane, __ATOMIC_ACQUIRE,
                                        __HIP_MEMORY_SCOPE_AGENT)
                    : tt;
                if (__all(v >= tt)) break;
            }
        }
        __syncthreads();
        const float* p = part + (size_t)(QP_ITERS & 1) * (NBLK * SLOT)
                       + (size_t)b * (16 * SLOT) + tid;   // tid<512: x-partials
        if (tid < 512) {
            float acc = gather16_sum_agent(p);
            stage[tid] = fminf(1.0f, 2.0f / (acc + 1e-8f));
        }
        __syncthreads();
        #pragma unroll
        for (int k = 0; k < 16; ++k)
            out[rowbase + cseg + 32*k] = x[k] * stage[cseg + 32*k];
    }
}

// ---------------------------------------------------------------------------
extern "C" void kernel_launch(void* const* d_in, const int* in_sizes, int n_in,
                              void* d_out, int out_size, void* d_ws, size_t ws_size,
                              hipStream_t stream)
{
    const float* nc = (const float*)d_in[0];  // n_emb_cur (16,512,128)
    const float* ec = (const float*)d_in[1];  // e_emb_cur
    const float* nn = (const float*)d_in[2];  // n_emb_nxt
    const float* en = (const float*)d_in[3];  // e_emb_nxt
    float* out = (float*)d_out;               // (16, 512*512) fp32

    float* ws = (float*)d_ws;
    const size_t QM_FLOATS = (size_t)BATCH * NN * MM;       // 4,194,304

    float* qm   = ws;
    float* part = ws + QM_FLOATS;                           // 2*NBLK*SLOT floats
    // zero region (cleared by row_norms blocks 0-8): sumq, sumq2, flags
    float* zreg  = part + (size_t)2 * NBLK * SLOT;
    float* sumq  = zreg;                                    // 16
    float* sumq2 = zreg + 16;                               // 16
    unsigned* flags = (unsigned*)(zreg + 32);               // 512
    float* rc    = zreg + ZFLOATS;                          // 8192
    float* rn    = rc + BATCH * MM;                         // 8192

    row_norms_kernel<<<BATCH * 512, 64, 0, stream>>>(nc, ec, nn, en, rc, rn, zreg);
    gemm_q_kernel<<<dim3(4, 8, BATCH), 256, 0, stream>>>(nc, ec, nn, en, rc, rn,
                                                         qm, sumq, sumq2);

    void* args[] = { (void*)&qm, (void*)&sumq, (void*)&sumq2,
                     (void*)&part, (void*)&flags, (void*)&out };
    hipLaunchCooperativeKernel((const void*)qp_iter_kernel,
                               dim3(NBLK), dim3(1024),
                               args, 0, stream);
}